// Round 6
// baseline (285.187 us; speedup 1.0000x reference)
//
#include <hip/hip_runtime.h>
#include <hip/hip_bf16.h>

typedef __bf16 bf16x8 __attribute__((ext_vector_type(8)));
typedef float f32x4 __attribute__((ext_vector_type(4)));
typedef unsigned short us4 __attribute__((ext_vector_type(4)));

#define NLOG2E -1.44269504088896340736f

__device__ __forceinline__ unsigned short f2bf(float f) {
    unsigned u = __float_as_uint(f);
    u += 0x7fffu + ((u >> 16) & 1u);   // round-to-nearest-even
    return (unsigned short)(u >> 16);
}

// ---- prep: fp32 -> bf16 (16B-chunk XOR swizzle) + row norms pre-scaled by -log2(e) ----
__global__ __launch_bounds__(256)
void rbf_prep(const float* __restrict__ X, const float* __restrict__ Y,
              unsigned short* __restrict__ Xb, unsigned short* __restrict__ Yb,
              float* __restrict__ x2n, float* __restrict__ y2n) {
    const int b = blockIdx.x;
    const float* src = (b < 128) ? X : Y;
    unsigned short* db = (b < 128) ? Xb : Yb;
    float* dn = (b < 128) ? x2n : y2n;
    const int r0 = (b & 127) * 64;
    const int t = threadIdx.x;
    const f32x4* s4 = (const f32x4*)(src + (size_t)r0 * 128);
#pragma unroll
    for (int i = 0; i < 8; ++i) {
        int idx = i * 256 + t;
        int r = idx >> 5, c4 = idx & 31;
        f32x4 v = s4[idx];
        us4 o;
        o.x = f2bf(v[0]); o.y = f2bf(v[1]); o.z = f2bf(v[2]); o.w = f2bf(v[3]);
        int pc = (c4 >> 1) ^ (r & 7);
        *(us4*)&db[(size_t)(r0 + r) * 128 + pc * 8 + (c4 & 1) * 4] = o;
    }
    if (t < 64) {
        const f32x4* row = (const f32x4*)(src + (size_t)(r0 + t) * 128);
        float s = 0.f;
#pragma unroll
        for (int c = 0; c < 32; ++c) {
            f32x4 v = row[c];
            s += v[0] * v[0] + v[1] * v[1] + v[2] * v[2] + v[3] * v[3];
        }
        dn[r0 + t] = NLOG2E * s;   // pre-scaled: arg = fma(2*log2e, xy, xn+yn)
    }
}

// ---- main: 64x64 tile, 32KB LDS -> 5 blocks/CU; wave-local restage (no 3rd barrier) ----
__global__ __launch_bounds__(256, 5)
void rbf_main(const unsigned short* __restrict__ Xb, const unsigned short* __restrict__ Yb,
              const float* __restrict__ x2n, const float* __restrict__ y2n,
              float* __restrict__ O) {
    __shared__ __align__(16) char smem[32768];
    unsigned short* Ab = (unsigned short*)smem;            // [64][128] bf16 swizzled, 16KB
    unsigned short* Bb = (unsigned short*)(smem + 16384);  // [64][128] bf16 swizzled, 16KB

    const int t = threadIdx.x, l = t & 63, w = t >> 6;
    const int col0 = blockIdx.x * 64, row0 = blockIdx.y * 64;

    const char* gA = (const char*)(Xb + (size_t)row0 * 128);
    const char* gB = (const char*)(Yb + (size_t)col0 * 128);
#pragma unroll
    for (int j = 0; j < 4; ++j) {
        int base = (w * 4 + j) * 1024;
        __builtin_amdgcn_global_load_lds(
            (const __attribute__((address_space(1))) void*)(gA + base + l * 16),
            (__attribute__((address_space(3))) void*)(smem + base), 16, 0, 0);
        __builtin_amdgcn_global_load_lds(
            (const __attribute__((address_space(1))) void*)(gB + base + l * 16),
            (__attribute__((address_space(3))) void*)(smem + 16384 + base), 16, 0, 0);
    }

    const int lr = l & 15, q = l >> 4;
    const int wr = (w >> 1) * 32, wc = (w & 1) * 32;   // 2x2 wave grid, wave tile 32x32

    f32x4 xn[2]; float yn[2];
#pragma unroll
    for (int m = 0; m < 2; ++m) xn[m] = *(const f32x4*)&x2n[row0 + wr + m * 16 + q * 4];
#pragma unroll
    for (int n = 0; n < 2; ++n) yn[n] = y2n[col0 + wc + n * 16 + lr];

    __syncthreads();

    f32x4 acc[2][2] = {};
#pragma unroll
    for (int k = 0; k < 4; ++k) {
        bf16x8 af[2], bv[2];
#pragma unroll
        for (int m = 0; m < 2; ++m) {
            int R = wr + m * 16 + lr;
            af[m] = *(const bf16x8*)((const char*)Ab + R * 256 + (((k << 2) + q) ^ (R & 7)) * 16);
        }
#pragma unroll
        for (int n = 0; n < 2; ++n) {
            int R = wc + n * 16 + lr;
            bv[n] = *(const bf16x8*)((const char*)Bb + R * 256 + (((k << 2) + q) ^ (R & 7)) * 16);
        }
#pragma unroll
        for (int m = 0; m < 2; ++m)
#pragma unroll
            for (int n = 0; n < 2; ++n)
                acc[m][n] = __builtin_amdgcn_mfma_f32_16x16x32_bf16(af[m], bv[n], acc[m][n], 0, 0, 0);
    }

    __syncthreads();   // all waves' A/B LDS reads complete before Ol aliases Ab

    // wave-local restage: Ol = per-wave [32][32] f32 (4KB), chunk-XOR swizzled.
    // write->read within the same wave: lgkmcnt ordering only, NO barrier needed.
    float* Ol = (float*)(smem + w * 4096);
#pragma unroll
    for (int m = 0; m < 2; ++m) {
#pragma unroll
        for (int n = 0; n < 2; ++n) {
            int col = n * 16 + lr;             // 0..31 local
            int lc = col >> 2;
            float ynv = yn[n];
#pragma unroll
            for (int i = 0; i < 4; ++i) {
                int row = m * 16 + q * 4 + i;  // 0..31 local
                float arg = fmaf(-2.0f * NLOG2E, acc[m][n][i], xn[m][i] + ynv);
                arg = fminf(arg, 0.f);         // sq >= 0  <=>  arg <= 0
                int pc = (lc ^ row) & 7;       // 2-way banked per instr (free)
                Ol[row * 32 + pc * 4 + (col & 3)] = exp2f(arg);
            }
        }
    }

    // store own 32x32 region: per wave-instr 8 full 128B lines, coalesced
#pragma unroll
    for (int it = 0; it < 4; ++it) {
        int r = it * 8 + (l >> 3);             // 0..31 local row
        int lc2 = l & 7;
        int pc = lc2 ^ (r & 7);
        f32x4 v = *(const f32x4*)((const char*)Ol + r * 128 + pc * 16);
        *(float4*)&O[(size_t)(row0 + wr + r) * 8192 + col0 + wc + lc2 * 4] = *(float4*)&v;
    }
}

extern "C" void kernel_launch(void* const* d_in, const int* in_sizes, int n_in,
                              void* d_out, int out_size, void* d_ws, size_t ws_size,
                              hipStream_t stream) {
    const float* X = (const float*)d_in[0];
    const float* Y = (const float*)d_in[1];
    float* O = (float*)d_out;
    const int N = in_sizes[0] / 128;          // 8192
    const int M = in_sizes[1] / 128;          // 8192
    unsigned short* Xb = (unsigned short*)d_ws;
    unsigned short* Yb = Xb + (size_t)N * 128;
    float* x2n = (float*)(Yb + (size_t)M * 128);
    float* y2n = x2n + N;
    rbf_prep<<<dim3((N + M) / 64), 256, 0, stream>>>(X, Y, Xb, Yb, x2n, y2n);
    rbf_main<<<dim3(M / 64, N / 64), 256, 0, stream>>>(Xb, Yb, x2n, y2n, O);
}

// Round 7
// 269.883 us; speedup vs baseline: 1.0567x; 1.0567x over previous
//
#include <hip/hip_runtime.h>
#include <hip/hip_bf16.h>

typedef __bf16 bf16x8 __attribute__((ext_vector_type(8)));
typedef float f32x4 __attribute__((ext_vector_type(4)));
typedef float f32x16 __attribute__((ext_vector_type(16)));
typedef unsigned short us4 __attribute__((ext_vector_type(4)));

#define NLOG2E  -1.44269504088896340736f
#define TWOLOG2E 2.88539008177792681472f

__device__ __forceinline__ unsigned short f2bf(float f) {
    unsigned u = __float_as_uint(f);
    u += 0x7fffu + ((u >> 16) & 1u);   // round-to-nearest-even
    return (unsigned short)(u >> 16);
}

// ---- prep: fp32 -> bf16 (16B-chunk XOR swizzle) + row norms pre-scaled by -log2(e) ----
__global__ __launch_bounds__(256)
void rbf_prep(const float* __restrict__ X, const float* __restrict__ Y,
              unsigned short* __restrict__ Xb, unsigned short* __restrict__ Yb,
              float* __restrict__ x2n, float* __restrict__ y2n) {
    const int b = blockIdx.x;
    const float* src = (b < 128) ? X : Y;
    unsigned short* db = (b < 128) ? Xb : Yb;
    float* dn = (b < 128) ? x2n : y2n;
    const int r0 = (b & 127) * 64;
    const int t = threadIdx.x;
    const f32x4* s4 = (const f32x4*)(src + (size_t)r0 * 128);
#pragma unroll
    for (int i = 0; i < 8; ++i) {
        int idx = i * 256 + t;
        int r = idx >> 5, c4 = idx & 31;
        f32x4 v = s4[idx];
        us4 o;
        o.x = f2bf(v[0]); o.y = f2bf(v[1]); o.z = f2bf(v[2]); o.w = f2bf(v[3]);
        int pc = (c4 >> 1) ^ (r & 7);
        *(us4*)&db[(size_t)(r0 + r) * 128 + pc * 8 + (c4 & 1) * 4] = o;
    }
    if (t < 64) {
        const f32x4* row = (const f32x4*)(src + (size_t)(r0 + t) * 128);
        float s = 0.f;
#pragma unroll
        for (int c = 0; c < 32; ++c) {
            f32x4 v = row[c];
            s += v[0] * v[0] + v[1] * v[1] + v[2] * v[2] + v[3] * v[3];
        }
        dn[r0 + t] = NLOG2E * s;   // arg = fma(2*log2e, xy, xnp+ynp), out = exp2(arg)
    }
}

// ---- main: 64x128 tile, 48KB LDS (3 blocks/CU), 32x32x16 MFMA.
//      C/D layout (col=lane&31, row=(reg&3)+8*(reg>>2)+4*(lane>>5)) makes every
//      global_store_dword cover two full aligned 128B lines -> NO LDS restage,
//      single barrier, stores spread through the exp2 epilogue. ----
__global__ __launch_bounds__(256, 3)
void rbf_main(const unsigned short* __restrict__ Xb, const unsigned short* __restrict__ Yb,
              const float* __restrict__ x2n, const float* __restrict__ y2n,
              float* __restrict__ O, int ldo) {
    __shared__ __align__(16) char smem[49152];
    // A: [64 rows][128 k] bf16 swizzled @ 0 (16KB); B: [128 cols][128 k] @ 16384 (32KB)

    const int t = threadIdx.x, l = t & 63, w = t >> 6;
    const int col0 = blockIdx.x * 128, row0 = blockIdx.y * 64;

    const char* gA = (const char*)(Xb + (size_t)row0 * 128);
    const char* gB = (const char*)(Yb + (size_t)col0 * 128);
#pragma unroll
    for (int j = 0; j < 4; ++j) {
        int base = (w * 4 + j) * 1024;
        __builtin_amdgcn_global_load_lds(
            (const __attribute__((address_space(1))) void*)(gA + base + l * 16),
            (__attribute__((address_space(3))) void*)(smem + base), 16, 0, 0);
    }
#pragma unroll
    for (int j = 0; j < 8; ++j) {
        int base = (w * 8 + j) * 1024;
        __builtin_amdgcn_global_load_lds(
            (const __attribute__((address_space(1))) void*)(gB + base + l * 16),
            (__attribute__((address_space(3))) void*)(smem + 16384 + base), 16, 0, 0);
    }

    const int ln = l & 31, hi = l >> 5;
    const int wr = (w >> 1) * 32, wcw = (w & 1) * 64;   // wave tile: 32 rows x 64 cols

    // norms (L2-hot, hide under staging): rows i+8g+4hi, cols per fragment
    f32x4 xv[4];
#pragma unroll
    for (int g = 0; g < 4; ++g)
        xv[g] = *(const f32x4*)&x2n[row0 + wr + 8 * g + 4 * hi];
    float ynp[2];
#pragma unroll
    for (int nf = 0; nf < 2; ++nf)
        ynp[nf] = y2n[col0 + wcw + nf * 32 + ln];

    __syncthreads();

    // K-loop: 8 steps of k=16. A frag: row=lane&31, k=(lane>>5)*8+j.
    // LDS chunk index lc = 2*kk + hi, physical chunk = lc ^ (row&7).
    f32x16 acc0 = {}, acc1 = {};
    const int RA = wr + ln;            // A local row
    const int C0 = wcw + ln;           // B local col, frag 0
    const int C1 = wcw + 32 + ln;      // frag 1
#pragma unroll
    for (int kk = 0; kk < 8; ++kk) {
        int lc = 2 * kk + hi;
        bf16x8 af = *(const bf16x8*)(smem + RA * 256 + ((lc ^ (RA & 7)) * 16));
        bf16x8 b0 = *(const bf16x8*)(smem + 16384 + C0 * 256 + ((lc ^ (C0 & 7)) * 16));
        bf16x8 b1 = *(const bf16x8*)(smem + 16384 + C1 * 256 + ((lc ^ (C1 & 7)) * 16));
        acc0 = __builtin_amdgcn_mfma_f32_32x32x16_bf16(af, b0, acc0, 0, 0, 0);
        acc1 = __builtin_amdgcn_mfma_f32_32x32x16_bf16(af, b1, acc1, 0, 0, 0);
    }

    // epilogue: arg = 2*log2e*xy + (xnp+ynp), clamp <=0, exp2 -> direct store.
    // One store instr = rows {r, r+4} x 32 consecutive cols = 2 full 128B lines.
#pragma unroll
    for (int nf = 0; nf < 2; ++nf) {
        float yb = ynp[nf];
        float* ob = &O[(size_t)(row0 + wr + 4 * hi) * ldo + col0 + wcw + nf * 32 + ln];
#pragma unroll
        for (int g = 0; g < 4; ++g) {
#pragma unroll
            for (int i = 0; i < 4; ++i) {
                float xy = (nf == 0) ? acc0[g * 4 + i] : acc1[g * 4 + i];
                float arg = fmaf(TWOLOG2E, xy, xv[g][i] + yb);
                arg = fminf(arg, 0.f);
                ob[(size_t)(8 * g + i) * ldo] = exp2f(arg);
            }
        }
    }
}

extern "C" void kernel_launch(void* const* d_in, const int* in_sizes, int n_in,
                              void* d_out, int out_size, void* d_ws, size_t ws_size,
                              hipStream_t stream) {
    const float* X = (const float*)d_in[0];
    const float* Y = (const float*)d_in[1];
    float* O = (float*)d_out;
    const int N = in_sizes[0] / 128;          // 8192
    const int M = in_sizes[1] / 128;          // 8192
    unsigned short* Xb = (unsigned short*)d_ws;
    unsigned short* Yb = Xb + (size_t)N * 128;
    float* x2n = (float*)(Yb + (size_t)M * 128);
    float* y2n = x2n + N;
    rbf_prep<<<dim3((N + M) / 64), 256, 0, stream>>>(X, Y, Xb, Yb, x2n, y2n);
    rbf_main<<<dim3(M / 128, N / 64), 256, 0, stream>>>(Xb, Yb, x2n, y2n, O, M);
}

// Round 8
// 266.886 us; speedup vs baseline: 1.0686x; 1.0112x over previous
//
#include <hip/hip_runtime.h>
#include <hip/hip_bf16.h>

typedef __bf16 bf16x8 __attribute__((ext_vector_type(8)));
typedef float f32x4 __attribute__((ext_vector_type(4)));
typedef float f32x16 __attribute__((ext_vector_type(16)));
typedef unsigned short us4 __attribute__((ext_vector_type(4)));

#define NLOG2E  -1.44269504088896340736f
#define TWOLOG2E 2.88539008177792681472f

__device__ __forceinline__ unsigned short f2bf(float f) {
    unsigned u = __float_as_uint(f);
    u += 0x7fffu + ((u >> 16) & 1u);   // round-to-nearest-even
    return (unsigned short)(u >> 16);
}

// ---- prep: 32-row blocks (2/CU), fp32 -> bf16 (16B-chunk XOR swizzle),
//      all-thread norm phase (8 threads/row + shfl_xor reduce) ----
__global__ __launch_bounds__(256)
void rbf_prep(const float* __restrict__ X, const float* __restrict__ Y,
              unsigned short* __restrict__ Xb, unsigned short* __restrict__ Yb,
              float* __restrict__ x2n, float* __restrict__ y2n) {
    const int b = blockIdx.x;                  // 0..255 -> X, 256..511 -> Y
    const float* src = (b < 256) ? X : Y;
    unsigned short* db = (b < 256) ? Xb : Yb;
    float* dn = (b < 256) ? x2n : y2n;
    const int r0 = (b & 255) * 32;
    const int t = threadIdx.x;

    // convert: 32 rows x 128 cols, coalesced f32x4, swizzled bf16 out
    const f32x4* s4 = (const f32x4*)(src + (size_t)r0 * 128);
#pragma unroll
    for (int i = 0; i < 4; ++i) {
        int idx = i * 256 + t;                 // 1024 float4 in block
        int r = idx >> 5, c4 = idx & 31;
        f32x4 v = s4[idx];
        us4 o;
        o.x = f2bf(v[0]); o.y = f2bf(v[1]); o.z = f2bf(v[2]); o.w = f2bf(v[3]);
        int pc = (c4 >> 1) ^ (r & 7);
        *(us4*)&db[(size_t)(r0 + r) * 128 + pc * 8 + (c4 & 1) * 4] = o;
    }

    // norms: 8 threads per row, 16 elems each (L1-hot), 8-lane butterfly reduce
    {
        int r = t >> 3, sub = t & 7;           // r: 0..31
        const f32x4* row = (const f32x4*)(src + (size_t)(r0 + r) * 128);
        float s = 0.f;
#pragma unroll
        for (int c = 0; c < 4; ++c) {
            f32x4 v = row[sub * 4 + c];
            s += v[0] * v[0] + v[1] * v[1] + v[2] * v[2] + v[3] * v[3];
        }
        s += __shfl_xor(s, 1);
        s += __shfl_xor(s, 2);
        s += __shfl_xor(s, 4);
        if (sub == 0) dn[r0 + r] = NLOG2E * s; // arg = fma(2*log2e, xy, xn+yn)
    }
}

// ---- main: 64x128 tile, 48KB LDS (3 blocks/CU), 32x32x16 MFMA, direct
//      full-line stores from acc — now nontemporal so the 256MB write stream
//      doesn't evict the staged inputs from L2 ----
__global__ __launch_bounds__(256, 3)
void rbf_main(const unsigned short* __restrict__ Xb, const unsigned short* __restrict__ Yb,
              const float* __restrict__ x2n, const float* __restrict__ y2n,
              float* __restrict__ O, int ldo) {
    __shared__ __align__(16) char smem[49152];
    // A: [64 rows][128 k] bf16 swizzled @ 0 (16KB); B: [128 cols][128 k] @ 16384 (32KB)

    const int t = threadIdx.x, l = t & 63, w = t >> 6;
    const int col0 = blockIdx.x * 128, row0 = blockIdx.y * 64;

    const char* gA = (const char*)(Xb + (size_t)row0 * 128);
    const char* gB = (const char*)(Yb + (size_t)col0 * 128);
#pragma unroll
    for (int j = 0; j < 4; ++j) {
        int base = (w * 4 + j) * 1024;
        __builtin_amdgcn_global_load_lds(
            (const __attribute__((address_space(1))) void*)(gA + base + l * 16),
            (__attribute__((address_space(3))) void*)(smem + base), 16, 0, 0);
    }
#pragma unroll
    for (int j = 0; j < 8; ++j) {
        int base = (w * 8 + j) * 1024;
        __builtin_amdgcn_global_load_lds(
            (const __attribute__((address_space(1))) void*)(gB + base + l * 16),
            (__attribute__((address_space(3))) void*)(smem + 16384 + base), 16, 0, 0);
    }

    const int ln = l & 31, hi = l >> 5;
    const int wr = (w >> 1) * 32, wcw = (w & 1) * 64;   // wave tile: 32 rows x 64 cols

    f32x4 xv[4];
#pragma unroll
    for (int g = 0; g < 4; ++g)
        xv[g] = *(const f32x4*)&x2n[row0 + wr + 8 * g + 4 * hi];
    float ynp[2];
#pragma unroll
    for (int nf = 0; nf < 2; ++nf)
        ynp[nf] = y2n[col0 + wcw + nf * 32 + ln];

    __syncthreads();

    // K-loop: 8 steps of k=16. A frag: row=lane&31, k=(lane>>5)*8+j.
    f32x16 acc0 = {}, acc1 = {};
    const int RA = wr + ln;
    const int C0 = wcw + ln;
    const int C1 = wcw + 32 + ln;
#pragma unroll
    for (int kk = 0; kk < 8; ++kk) {
        int lc = 2 * kk + hi;
        bf16x8 af = *(const bf16x8*)(smem + RA * 256 + ((lc ^ (RA & 7)) * 16));
        bf16x8 b0 = *(const bf16x8*)(smem + 16384 + C0 * 256 + ((lc ^ (C0 & 7)) * 16));
        bf16x8 b1 = *(const bf16x8*)(smem + 16384 + C1 * 256 + ((lc ^ (C1 & 7)) * 16));
        acc0 = __builtin_amdgcn_mfma_f32_32x32x16_bf16(af, b0, acc0, 0, 0, 0);
        acc1 = __builtin_amdgcn_mfma_f32_32x32x16_bf16(af, b1, acc1, 0, 0, 0);
    }

    // epilogue: arg = 2*log2e*xy + (xnp+ynp), clamp <=0, exp2 -> nt store.
    // One store instr = rows {r, r+4} x 32 consecutive cols = 2 full 128B lines.
#pragma unroll
    for (int nf = 0; nf < 2; ++nf) {
        float yb = ynp[nf];
        float* ob = &O[(size_t)(row0 + wr + 4 * hi) * ldo + col0 + wcw + nf * 32 + ln];
#pragma unroll
        for (int g = 0; g < 4; ++g) {
#pragma unroll
            for (int i = 0; i < 4; ++i) {
                float xy = (nf == 0) ? acc0[g * 4 + i] : acc1[g * 4 + i];
                float arg = fmaf(TWOLOG2E, xy, xv[g][i] + yb);
                arg = fminf(arg, 0.f);
                __builtin_nontemporal_store(exp2f(arg), &ob[(size_t)(8 * g + i) * ldo]);
            }
        }
    }
}

extern "C" void kernel_launch(void* const* d_in, const int* in_sizes, int n_in,
                              void* d_out, int out_size, void* d_ws, size_t ws_size,
                              hipStream_t stream) {
    const float* X = (const float*)d_in[0];
    const float* Y = (const float*)d_in[1];
    float* O = (float*)d_out;
    const int N = in_sizes[0] / 128;          // 8192
    const int M = in_sizes[1] / 128;          // 8192
    unsigned short* Xb = (unsigned short*)d_ws;
    unsigned short* Yb = Xb + (size_t)N * 128;
    float* x2n = (float*)(Yb + (size_t)M * 128);
    float* y2n = x2n + N;
    rbf_prep<<<dim3((N + M) / 32), 256, 0, stream>>>(X, Y, Xb, Yb, x2n, y2n);
    rbf_main<<<dim3(M / 128, N / 64), 256, 0, stream>>>(Xb, Yb, x2n, y2n, O, M);
}